// Round 1
// baseline (291.123 us; speedup 1.0000x reference)
//
#include <hip/hip_runtime.h>
#include <hip/hip_bf16.h>

typedef __bf16 bf16x8 __attribute__((ext_vector_type(8)));
typedef float f32x4 __attribute__((ext_vector_type(4)));

#define D_ 128
#define T_ 2048
#define B_ 4
#define H_ 4
#define NB_ 2

// ---------------------------------------------------------------------------
// Weight prep: fp32 [NB][128][128] (k-major) -> bf16 transposed Wt[j][i][n][k]
// j = {q,k,v,o,w1,w2}
// ---------------------------------------------------------------------------
__global__ __launch_bounds__(256) void prep_weights(
    const float* __restrict__ Wq, const float* __restrict__ Wk,
    const float* __restrict__ Wv, const float* __restrict__ Wo,
    const float* __restrict__ W1, const float* __restrict__ W2,
    __bf16* __restrict__ wt)
{
  int tid = blockIdx.x * 256 + threadIdx.x;   // < 6*NB*128*128
  int j   = tid >> 15;                         // which weight family
  int rem = tid & 32767;                       // i*16384 + n*128 + k
  int i   = rem >> 14;
  int n   = (rem >> 7) & 127;
  int kk  = rem & 127;
  const float* srcs[6] = {Wq, Wk, Wv, Wo, W1, W2};
  wt[tid] = (__bf16)srcs[j][i * 16384 + kk * 128 + n];
}

// ---------------------------------------------------------------------------
// x = inputs + pos_encoding; out = LN(x, g, b) as bf16. One wave per row.
// PE quirk (faithful to ref): every column i has its own freq 10000^(2i/128),
// even i -> sin, odd i -> cos.
// ---------------------------------------------------------------------------
__global__ __launch_bounds__(256) void pos_ln(
    const float* __restrict__ x, const float* __restrict__ g,
    const float* __restrict__ bb, __bf16* __restrict__ out)
{
  int w = threadIdx.x >> 6, lane = threadIdx.x & 63;
  int row = blockIdx.x * 4 + w;              // 0..8191
  int t = row & (T_ - 1);
  float v[2]; float s = 0.f, s2 = 0.f;
  #pragma unroll
  for (int e = 0; e < 2; e++) {
    int c = lane * 2 + e;
    // 1/10000^(2c/128) = 2^(-log2(10000)*c/64)
    float arg = (float)t * exp2f(-0.20762050593045952f * (float)c);
    float pe = (c & 1) ? cosf(arg) : sinf(arg);
    float val = x[row * D_ + c] + pe;
    v[e] = val; s += val; s2 += val * val;
  }
  for (int m = 1; m < 64; m <<= 1) {
    s += __shfl_xor(s, m, 64);
    s2 += __shfl_xor(s2, m, 64);
  }
  float mu = s * (1.f / D_);
  float var = s2 * (1.f / D_) - mu * mu;
  float rstd = rsqrtf(var + 1e-3f);
  #pragma unroll
  for (int e = 0; e < 2; e++) {
    int c = lane * 2 + e;
    out[row * D_ + c] = (__bf16)((v[e] - mu) * rstd * g[c] + bb[c]);
  }
}

// ---------------------------------------------------------------------------
// GEMM: out[8192,128] = A[8192,128] @ W[128,128] + bias, with epilogues.
// One wave per block, 16 rows x 128 cols, K=128 (4 mfma k-steps).
// Wt is transposed weight (Wt[n][k]) so B-frags are contiguous b128 loads.
// mfma_f32_16x16x32_bf16 layouts:
//   A: lane holds A[lane%16][8*(lane/16)+e]
//   B: lane holds B[8*(lane/16)+e][lane%16]
//   C/D: lane holds D[(lane/16)*4+r][lane%16]
// ---------------------------------------------------------------------------
enum { EP_PLAIN = 0, EP_RELU, EP_VT, EP_LN, EP_LN_OUT };

template <int EP>
__global__ __launch_bounds__(64) void gemm128(
    const __bf16* __restrict__ A, const __bf16* __restrict__ Wt,
    const float* __restrict__ bias,
    __bf16* __restrict__ outb, float* __restrict__ outf,
    const __bf16* __restrict__ resid,
    const float* __restrict__ g, const float* __restrict__ beta)
{
  int lane = threadIdx.x;
  int m0 = blockIdx.x * 16;
  int lr = lane & 15, kg = lane >> 4;

  const __bf16* arow = A + (m0 + lr) * D_ + kg * 8;
  bf16x8 af[4];
  #pragma unroll
  for (int ks = 0; ks < 4; ks++) af[ks] = *(const bf16x8*)(arow + ks * 32);

  f32x4 acc[8];
  #pragma unroll
  for (int nt = 0; nt < 8; nt++) acc[nt] = (f32x4){0.f, 0.f, 0.f, 0.f};

  #pragma unroll
  for (int nt = 0; nt < 8; nt++) {
    const __bf16* wrow = Wt + (nt * 16 + lr) * D_ + kg * 8;
    #pragma unroll
    for (int ks = 0; ks < 4; ks++) {
      bf16x8 bfr = *(const bf16x8*)(wrow + ks * 32);
      acc[nt] = __builtin_amdgcn_mfma_f32_16x16x32_bf16(af[ks], bfr, acc[nt], 0, 0, 0);
    }
  }

  float xv[8][4];
  #pragma unroll
  for (int nt = 0; nt < 8; nt++) {
    float bcol = bias[nt * 16 + lr];
    #pragma unroll
    for (int r = 0; r < 4; r++) xv[nt][r] = acc[nt][r] + bcol;
  }

  if constexpr (EP == EP_PLAIN || EP == EP_RELU) {
    #pragma unroll
    for (int nt = 0; nt < 8; nt++)
      #pragma unroll
      for (int r = 0; r < 4; r++) {
        int row = m0 + kg * 4 + r, col = nt * 16 + lr;
        float y = xv[nt][r];
        if constexpr (EP == EP_RELU) y = fmaxf(y, 0.f);
        outb[row * D_ + col] = (__bf16)y;
      }
  } else if constexpr (EP == EP_VT) {
    // store V transposed: vT[b][h][dk][t]
    #pragma unroll
    for (int nt = 0; nt < 8; nt++)
      #pragma unroll
      for (int r = 0; r < 4; r++) {
        int row = m0 + kg * 4 + r, col = nt * 16 + lr;
        int b = row >> 11, t = row & (T_ - 1);
        int h = col >> 5, dk = col & 31;
        outb[((b * H_ + h) * 32 + dk) * T_ + t] = (__bf16)xv[nt][r];
      }
  } else {
    if (resid) {
      #pragma unroll
      for (int nt = 0; nt < 8; nt++)
        #pragma unroll
        for (int r = 0; r < 4; r++)
          xv[nt][r] += (float)resid[(m0 + kg * 4 + r) * D_ + nt * 16 + lr];
    }
    float s[4] = {0, 0, 0, 0}, s2[4] = {0, 0, 0, 0};
    #pragma unroll
    for (int nt = 0; nt < 8; nt++)
      #pragma unroll
      for (int r = 0; r < 4; r++) {
        s[r] += xv[nt][r];
        s2[r] += xv[nt][r] * xv[nt][r];
      }
    #pragma unroll
    for (int r = 0; r < 4; r++)
      for (int m = 1; m < 16; m <<= 1) {
        s[r] += __shfl_xor(s[r], m, 64);
        s2[r] += __shfl_xor(s2[r], m, 64);
      }
    #pragma unroll
    for (int nt = 0; nt < 8; nt++) {
      float gc = g[nt * 16 + lr], bc = beta[nt * 16 + lr];
      #pragma unroll
      for (int r = 0; r < 4; r++) {
        float mu = s[r] * (1.f / D_);
        float var = s2[r] * (1.f / D_) - mu * mu;
        float rstd = rsqrtf(var + 1e-3f);
        float y = (xv[nt][r] - mu) * rstd * gc + bc;
        int row = m0 + kg * 4 + r, col = nt * 16 + lr;
        if constexpr (EP == EP_LN) outb[row * D_ + col] = (__bf16)y;
        else outf[row * D_ + col] = y;
      }
    }
  }
}

// ---------------------------------------------------------------------------
// Flash attention: 1 wave per (b,h,16-row q-tile). DK=32 (one mfma K).
// S-tile C-layout: row=(lane/16)*4+r (q), col=lane%16 (key). Online softmax
// with shuffle row-reduce over the 16-lane col group; P transposed to A-frag
// layout via per-wave LDS.
// ---------------------------------------------------------------------------
__global__ __launch_bounds__(256) void attn_kernel(
    const __bf16* __restrict__ q, const __bf16* __restrict__ k,
    const __bf16* __restrict__ vT, __bf16* __restrict__ ctx)
{
  __shared__ __attribute__((aligned(16))) __bf16 pbuf[4][16][32];
  int w = threadIdx.x >> 6, lane = threadIdx.x & 63;
  int wave = blockIdx.x * 4 + w;            // 0..2047
  int qt = wave & 127;
  int bh = wave >> 7;
  int b = bh >> 2, h = bh & 3;
  int lr = lane & 15, kg = lane >> 4;

  int qrow = b * T_ + qt * 16 + lr;
  bf16x8 qf = *(const bf16x8*)(q + qrow * D_ + h * 32 + kg * 8);
  const __bf16* kbase = k + (b * T_) * D_ + h * 32 + kg * 8;
  const __bf16* vbase = vT + (size_t)(b * H_ + h) * 32 * T_;

  float mstate[4] = {-1e30f, -1e30f, -1e30f, -1e30f};
  float lstate[4] = {0.f, 0.f, 0.f, 0.f};
  f32x4 acc0 = {0.f, 0.f, 0.f, 0.f}, acc1 = {0.f, 0.f, 0.f, 0.f};
  const float scale = 0.17677669529663687f;  // 1/sqrt(32)
  const f32x4 zero = {0.f, 0.f, 0.f, 0.f};

  for (int k0 = 0; k0 < T_; k0 += 32) {
    bf16x8 kf0 = *(const bf16x8*)(kbase + (k0 + lr) * D_);
    bf16x8 kf1 = *(const bf16x8*)(kbase + (k0 + 16 + lr) * D_);
    f32x4 s0 = __builtin_amdgcn_mfma_f32_16x16x32_bf16(qf, kf0, zero, 0, 0, 0);
    f32x4 s1 = __builtin_amdgcn_mfma_f32_16x16x32_bf16(qf, kf1, zero, 0, 0, 0);

    #pragma unroll
    for (int r = 0; r < 4; r++) {
      float s0r = s0[r] * scale, s1r = s1[r] * scale;
      float mt = fmaxf(s0r, s1r);
      for (int msk = 1; msk < 16; msk <<= 1) mt = fmaxf(mt, __shfl_xor(mt, msk, 64));
      float mnew = fmaxf(mstate[r], mt);
      float corr = __expf(mstate[r] - mnew);
      float p0 = __expf(s0r - mnew);
      float p1 = __expf(s1r - mnew);
      float rs = p0 + p1;
      for (int msk = 1; msk < 16; msk <<= 1) rs += __shfl_xor(rs, msk, 64);
      lstate[r] = lstate[r] * corr + rs;
      mstate[r] = mnew;
      acc0[r] *= corr; acc1[r] *= corr;
      pbuf[w][kg * 4 + r][lr] = (__bf16)p0;
      pbuf[w][kg * 4 + r][16 + lr] = (__bf16)p1;
    }
    bf16x8 pa = *(const bf16x8*)(&pbuf[w][lr][kg * 8]);
    bf16x8 v0 = *(const bf16x8*)(vbase + lr * T_ + k0 + kg * 8);
    bf16x8 v1 = *(const bf16x8*)(vbase + (16 + lr) * T_ + k0 + kg * 8);
    acc0 = __builtin_amdgcn_mfma_f32_16x16x32_bf16(pa, v0, acc0, 0, 0, 0);
    acc1 = __builtin_amdgcn_mfma_f32_16x16x32_bf16(pa, v1, acc1, 0, 0, 0);
  }

  #pragma unroll
  for (int r = 0; r < 4; r++) {
    int row = b * T_ + qt * 16 + kg * 4 + r;
    float inv = 1.0f / lstate[r];   // renormalize (sum_p+1e-8 == 1.0f in fp32)
    ctx[row * D_ + h * 32 + lr] = (__bf16)(acc0[r] * inv);
    ctx[row * D_ + h * 32 + 16 + lr] = (__bf16)(acc1[r] * inv);
  }
}

// ---------------------------------------------------------------------------
extern "C" void kernel_launch(void* const* d_in, const int* in_sizes, int n_in,
                              void* d_out, int out_size, void* d_ws, size_t ws_size,
                              hipStream_t stream)
{
  const float* inputs = (const float*)d_in[0];
  const float* Wq = (const float*)d_in[1];
  const float* bq = (const float*)d_in[2];
  const float* Wk = (const float*)d_in[3];
  const float* bk = (const float*)d_in[4];
  const float* Wv = (const float*)d_in[5];
  const float* bv = (const float*)d_in[6];
  const float* Wo = (const float*)d_in[7];
  const float* bo = (const float*)d_in[8];
  const float* W1 = (const float*)d_in[9];
  const float* b1 = (const float*)d_in[10];
  const float* W2 = (const float*)d_in[11];
  const float* b2 = (const float*)d_in[12];
  const float* ln_g = (const float*)d_in[13];
  const float* ln_b = (const float*)d_in[14];
  float* out = (float*)d_out;

  char* ws = (char*)d_ws;
  size_t off = 0;
  auto alloc = [&](size_t bytes) {
    void* p = ws + off;
    off = (off + bytes + 255) & ~(size_t)255;
    return p;
  };
  const size_t ACT = (size_t)8192 * 128 * sizeof(__bf16);  // 2 MB
  __bf16* wt   = (__bf16*)alloc((size_t)6 * NB_ * 128 * 128 * sizeof(__bf16));
  __bf16* hln1 = (__bf16*)alloc(ACT);
  __bf16* qb   = (__bf16*)alloc(ACT);
  __bf16* kb   = (__bf16*)alloc(ACT);
  __bf16* vb   = (__bf16*)alloc(ACT);
  __bf16* ctxb = (__bf16*)alloc(ACT);
  __bf16* hln2 = (__bf16*)alloc(ACT);
  __bf16* t1b  = (__bf16*)alloc(ACT);

  prep_weights<<<768, 256, 0, stream>>>(Wq, Wk, Wv, Wo, W1, W2, wt);
  pos_ln<<<2048, 256, 0, stream>>>(inputs, ln_g, ln_b, hln1);

  for (int i = 0; i < NB_; i++) {
    const __bf16* wtq = wt + (size_t)(0 * NB_ + i) * 16384;
    const __bf16* wtk = wt + (size_t)(1 * NB_ + i) * 16384;
    const __bf16* wtv = wt + (size_t)(2 * NB_ + i) * 16384;
    const __bf16* wto = wt + (size_t)(3 * NB_ + i) * 16384;
    const __bf16* wt1 = wt + (size_t)(4 * NB_ + i) * 16384;
    const __bf16* wt2 = wt + (size_t)(5 * NB_ + i) * 16384;

    gemm128<EP_PLAIN><<<512, 64, 0, stream>>>(hln1, wtq, bq + i * 128, qb, nullptr, nullptr, nullptr, nullptr);
    gemm128<EP_PLAIN><<<512, 64, 0, stream>>>(hln1, wtk, bk + i * 128, kb, nullptr, nullptr, nullptr, nullptr);
    gemm128<EP_VT><<<512, 64, 0, stream>>>(hln1, wtv, bv + i * 128, vb, nullptr, nullptr, nullptr, nullptr);
    attn_kernel<<<512, 256, 0, stream>>>(qb, kb, vb, ctxb);
    // h = ctx@Wo + bo, then pre-FFN LN -> hln2 (bf16)
    gemm128<EP_LN><<<512, 64, 0, stream>>>(ctxb, wto, bo + i * 128, hln2, nullptr, nullptr,
                                           ln_g + (2 * i + 1) * 128, ln_b + (2 * i + 1) * 128);
    // t1 = relu(hln2@W1 + b1)
    gemm128<EP_RELU><<<512, 64, 0, stream>>>(hln2, wt1, b1 + i * 128, t1b, nullptr, nullptr, nullptr, nullptr);
    // h = hln2 + t1@W2 + b2, then next LN (block0 -> hln1 for block1; block1 -> final LN -> fp32 out)
    if (i == 0) {
      gemm128<EP_LN><<<512, 64, 0, stream>>>(t1b, wt2, b2 + i * 128, hln1, nullptr, hln2,
                                             ln_g + 2 * 128, ln_b + 2 * 128);
    } else {
      gemm128<EP_LN_OUT><<<512, 64, 0, stream>>>(t1b, wt2, b2 + i * 128, nullptr, out, hln2,
                                                 ln_g + 3 * 128, ln_b + 3 * 128);
    }
  }
}

// Round 3
// 258.352 us; speedup vs baseline: 1.1268x; 1.1268x over previous
//
#include <hip/hip_runtime.h>
#include <hip/hip_bf16.h>

typedef __bf16 bf16x8 __attribute__((ext_vector_type(8)));
typedef __bf16 bf16x4 __attribute__((ext_vector_type(4)));
typedef float f32x4 __attribute__((ext_vector_type(4)));

#define D_ 128
#define T_ 2048
#define B_ 4
#define H_ 4
#define NB_ 2

// ---------------------------------------------------------------------------
// Weight prep: fp32 [NB][128][128] (k-major) -> bf16 transposed Wt[j][i][n][k]
// ---------------------------------------------------------------------------
__global__ __launch_bounds__(256) void prep_weights(
    const float* __restrict__ Wq, const float* __restrict__ Wk,
    const float* __restrict__ Wv, const float* __restrict__ Wo,
    const float* __restrict__ W1, const float* __restrict__ W2,
    __bf16* __restrict__ wt)
{
  int tid = blockIdx.x * 256 + threadIdx.x;   // < 6*NB*128*128
  int j   = tid >> 15;
  int rem = tid & 32767;
  int i   = rem >> 14;
  int n   = (rem >> 7) & 127;
  int kk  = rem & 127;
  const float* srcs[6] = {Wq, Wk, Wv, Wo, W1, W2};
  wt[tid] = (__bf16)srcs[j][i * 16384 + kk * 128 + n];
}

// ---------------------------------------------------------------------------
// x = inputs + pos_encoding; out = LN(x) as bf16. One wave per row.
// ---------------------------------------------------------------------------
__global__ __launch_bounds__(256) void pos_ln(
    const float* __restrict__ x, const float* __restrict__ g,
    const float* __restrict__ bb, __bf16* __restrict__ out)
{
  int w = threadIdx.x >> 6, lane = threadIdx.x & 63;
  int row = blockIdx.x * 4 + w;
  int t = row & (T_ - 1);
  float v[2]; float s = 0.f, s2 = 0.f;
  #pragma unroll
  for (int e = 0; e < 2; e++) {
    int c = lane * 2 + e;
    float arg = (float)t * exp2f(-0.20762050593045952f * (float)c);
    float pe = (c & 1) ? cosf(arg) : sinf(arg);
    float val = x[row * D_ + c] + pe;
    v[e] = val; s += val; s2 += val * val;
  }
  for (int m = 1; m < 64; m <<= 1) {
    s += __shfl_xor(s, m, 64);
    s2 += __shfl_xor(s2, m, 64);
  }
  float mu = s * (1.f / D_);
  float var = s2 * (1.f / D_) - mu * mu;
  float rstd = rsqrtf(var + 1e-3f);
  #pragma unroll
  for (int e = 0; e < 2; e++) {
    int c = lane * 2 + e;
    out[row * D_ + c] = (__bf16)((v[e] - mu) * rstd * g[c] + bb[c]);
  }
}

// ---------------------------------------------------------------------------
// Fused QKV: grid (512, 3). y=0:Q plain, y=1:K plain, y=2:V transposed store.
// mfma_f32_16x16x32_bf16 layouts:
//   A: lane holds A[lane%16][8*(lane/16)+e]
//   B: lane holds B[8*(lane/16)+e][lane%16]
//   C/D: lane holds D[(lane/16)*4+r][lane%16]
// ---------------------------------------------------------------------------
__global__ __launch_bounds__(64) void gemm_qkv(
    const __bf16* __restrict__ A, const __bf16* __restrict__ wtb,
    const float* __restrict__ bq, const float* __restrict__ bk,
    const float* __restrict__ bv,
    __bf16* __restrict__ qo, __bf16* __restrict__ ko, __bf16* __restrict__ vo)
{
  int lane = threadIdx.x;
  int m0 = blockIdx.x * 16;
  int which = blockIdx.y;
  int lr = lane & 15, kg = lane >> 4;
  const __bf16* Wt = wtb + (size_t)which * (NB_ * 16384);
  const float* bias = which == 0 ? bq : which == 1 ? bk : bv;

  const __bf16* arow = A + (size_t)(m0 + lr) * D_ + kg * 8;
  bf16x8 af[4];
  #pragma unroll
  for (int ks = 0; ks < 4; ks++) af[ks] = *(const bf16x8*)(arow + ks * 32);

  f32x4 acc[8];
  #pragma unroll
  for (int nt = 0; nt < 8; nt++) acc[nt] = (f32x4){0.f, 0.f, 0.f, 0.f};
  #pragma unroll
  for (int nt = 0; nt < 8; nt++) {
    const __bf16* wrow = Wt + (size_t)(nt * 16 + lr) * D_ + kg * 8;
    #pragma unroll
    for (int ks = 0; ks < 4; ks++) {
      bf16x8 bfr = *(const bf16x8*)(wrow + ks * 32);
      acc[nt] = __builtin_amdgcn_mfma_f32_16x16x32_bf16(af[ks], bfr, acc[nt], 0, 0, 0);
    }
  }

  if (which == 2) {
    #pragma unroll
    for (int nt = 0; nt < 8; nt++) {
      float bcol = bias[nt * 16 + lr];
      #pragma unroll
      for (int r = 0; r < 4; r++) {
        int row = m0 + kg * 4 + r, col = nt * 16 + lr;
        int b = row >> 11, t = row & (T_ - 1);
        int h = col >> 5, dk = col & 31;
        vo[((size_t)(b * H_ + h) * 32 + dk) * T_ + t] = (__bf16)(acc[nt][r] + bcol);
      }
    }
  } else {
    __bf16* outp = which ? ko : qo;
    #pragma unroll
    for (int nt = 0; nt < 8; nt++) {
      float bcol = bias[nt * 16 + lr];
      #pragma unroll
      for (int r = 0; r < 4; r++)
        outp[(size_t)(m0 + kg * 4 + r) * D_ + nt * 16 + lr] = (__bf16)(acc[nt][r] + bcol);
    }
  }
}

// ---------------------------------------------------------------------------
// GEMM + LayerNorm epilogue (for Wo): out = LN(A@Wt + bias) as bf16.
// ---------------------------------------------------------------------------
__global__ __launch_bounds__(64) void gemm_ln(
    const __bf16* __restrict__ A, const __bf16* __restrict__ Wt,
    const float* __restrict__ bias, const float* __restrict__ g,
    const float* __restrict__ beta, __bf16* __restrict__ outb)
{
  int lane = threadIdx.x;
  int m0 = blockIdx.x * 16;
  int lr = lane & 15, kg = lane >> 4;

  const __bf16* arow = A + (size_t)(m0 + lr) * D_ + kg * 8;
  bf16x8 af[4];
  #pragma unroll
  for (int ks = 0; ks < 4; ks++) af[ks] = *(const bf16x8*)(arow + ks * 32);

  f32x4 acc[8];
  #pragma unroll
  for (int nt = 0; nt < 8; nt++) acc[nt] = (f32x4){0.f, 0.f, 0.f, 0.f};
  #pragma unroll
  for (int nt = 0; nt < 8; nt++) {
    const __bf16* wrow = Wt + (size_t)(nt * 16 + lr) * D_ + kg * 8;
    #pragma unroll
    for (int ks = 0; ks < 4; ks++) {
      bf16x8 bfr = *(const bf16x8*)(wrow + ks * 32);
      acc[nt] = __builtin_amdgcn_mfma_f32_16x16x32_bf16(af[ks], bfr, acc[nt], 0, 0, 0);
    }
  }

  float xv[8][4];
  float s[4] = {0, 0, 0, 0}, s2[4] = {0, 0, 0, 0};
  #pragma unroll
  for (int nt = 0; nt < 8; nt++) {
    float bcol = bias[nt * 16 + lr];
    #pragma unroll
    for (int r = 0; r < 4; r++) {
      float y = acc[nt][r] + bcol;
      xv[nt][r] = y; s[r] += y; s2[r] += y * y;
    }
  }
  #pragma unroll
  for (int r = 0; r < 4; r++)
    for (int m = 1; m < 16; m <<= 1) {
      s[r] += __shfl_xor(s[r], m, 64);
      s2[r] += __shfl_xor(s2[r], m, 64);
    }
  #pragma unroll
  for (int nt = 0; nt < 8; nt++) {
    float gc = g[nt * 16 + lr], bc = beta[nt * 16 + lr];
    #pragma unroll
    for (int r = 0; r < 4; r++) {
      float mu = s[r] * (1.f / D_);
      float var = s2[r] * (1.f / D_) - mu * mu;
      float rstd = rsqrtf(var + 1e-3f);
      outb[(size_t)(m0 + kg * 4 + r) * D_ + nt * 16 + lr] =
          (__bf16)((xv[nt][r] - mu) * rstd * gc + bc);
    }
  }
}

// ---------------------------------------------------------------------------
// Fused FFN: t1 = relu(A@W1+b1) -> LDS (swizzled transpose) -> h = A + t1@W2+b2
// -> LN -> outb (bf16) or outf (fp32 final).
// ---------------------------------------------------------------------------
__global__ __launch_bounds__(64) void ffn_fused(
    const __bf16* __restrict__ A, const __bf16* __restrict__ wt1,
    const __bf16* __restrict__ wt2, const float* __restrict__ b1,
    const float* __restrict__ b2, const float* __restrict__ g,
    const float* __restrict__ beta, __bf16* __restrict__ outb,
    float* __restrict__ outf)
{
  __shared__ __attribute__((aligned(16))) __bf16 tbuf[16][128];
  int lane = threadIdx.x;
  int m0 = blockIdx.x * 16;
  int lr = lane & 15, kg = lane >> 4;

  const __bf16* arow = A + (size_t)(m0 + lr) * D_ + kg * 8;
  bf16x8 af[4];
  #pragma unroll
  for (int ks = 0; ks < 4; ks++) af[ks] = *(const bf16x8*)(arow + ks * 32);

  f32x4 acc[8];
  #pragma unroll
  for (int nt = 0; nt < 8; nt++) acc[nt] = (f32x4){0.f, 0.f, 0.f, 0.f};
  #pragma unroll
  for (int nt = 0; nt < 8; nt++) {
    const __bf16* wrow = wt1 + (size_t)(nt * 16 + lr) * D_ + kg * 8;
    #pragma unroll
    for (int ks = 0; ks < 4; ks++) {
      bf16x8 bfr = *(const bf16x8*)(wrow + ks * 32);
      acc[nt] = __builtin_amdgcn_mfma_f32_16x16x32_bf16(af[ks], bfr, acc[nt], 0, 0, 0);
    }
  }
  // relu + swizzled LDS transpose store: t1[row][col] at [row][col ^ ((row&7)<<3)]
  #pragma unroll
  for (int nt = 0; nt < 8; nt++) {
    float bcol = b1[nt * 16 + lr];
    #pragma unroll
    for (int r = 0; r < 4; r++) {
      int row = kg * 4 + r, col = nt * 16 + lr;
      ((__bf16*)tbuf)[row * 128 + (col ^ ((row & 7) << 3))] =
          (__bf16)fmaxf(acc[nt][r] + bcol, 0.f);
    }
  }
  // read t1 A-frags (row = lr)
  int swz = (lr & 7) << 3;
  bf16x8 a2[4];
  #pragma unroll
  for (int ks = 0; ks < 4; ks++)
    a2[ks] = *(const bf16x8*)((const __bf16*)tbuf + lr * 128 + ((ks * 32 + kg * 8) ^ swz));

  f32x4 acc2[8];
  #pragma unroll
  for (int nt = 0; nt < 8; nt++) acc2[nt] = (f32x4){0.f, 0.f, 0.f, 0.f};
  #pragma unroll
  for (int nt = 0; nt < 8; nt++) {
    const __bf16* wrow = wt2 + (size_t)(nt * 16 + lr) * D_ + kg * 8;
    #pragma unroll
    for (int ks = 0; ks < 4; ks++) {
      bf16x8 bfr = *(const bf16x8*)(wrow + ks * 32);
      acc2[nt] = __builtin_amdgcn_mfma_f32_16x16x32_bf16(a2[ks], bfr, acc2[nt], 0, 0, 0);
    }
  }
  // residual + LN
  float xv[8][4];
  float s[4] = {0, 0, 0, 0}, s2[4] = {0, 0, 0, 0};
  #pragma unroll
  for (int nt = 0; nt < 8; nt++) {
    float bcol = b2[nt * 16 + lr];
    #pragma unroll
    for (int r = 0; r < 4; r++) {
      float y = acc2[nt][r] + bcol +
                (float)A[(size_t)(m0 + kg * 4 + r) * D_ + nt * 16 + lr];
      xv[nt][r] = y; s[r] += y; s2[r] += y * y;
    }
  }
  #pragma unroll
  for (int r = 0; r < 4; r++)
    for (int m = 1; m < 16; m <<= 1) {
      s[r] += __shfl_xor(s[r], m, 64);
      s2[r] += __shfl_xor(s2[r], m, 64);
    }
  #pragma unroll
  for (int nt = 0; nt < 8; nt++) {
    float gc = g[nt * 16 + lr], bc = beta[nt * 16 + lr];
    #pragma unroll
    for (int r = 0; r < 4; r++) {
      float mu = s[r] * (1.f / D_);
      float var = s2[r] * (1.f / D_) - mu * mu;
      float rstd = rsqrtf(var + 1e-3f);
      float y = (xv[nt][r] - mu) * rstd * gc + bc;
      size_t idx = (size_t)(m0 + kg * 4 + r) * D_ + nt * 16 + lr;
      if (outb) outb[idx] = (__bf16)y;
      else outf[idx] = y;
    }
  }
}

// ---------------------------------------------------------------------------
// Flash attention, swapped layout. Block = 4 waves = 2 q-tiles x 2 KV-halves.
// S^T = mfma(K_frag, Q_frag): lane holds scores for q = lane&15,
// keys kb*16 + (lane>>4)*4 + r  ->  softmax row-reduce = in-reg + 2 shuffles.
// PV: O^T = V^T @ P^T, P staged in per-wave XOR-swizzled LDS.
// ---------------------------------------------------------------------------
__global__ __launch_bounds__(256) void attn2(
    const __bf16* __restrict__ q, const __bf16* __restrict__ k,
    const __bf16* __restrict__ vT, __bf16* __restrict__ ctx)
{
  __shared__ __attribute__((aligned(16))) __bf16 pbuf[4][16][64];
  __shared__ float mbuf[2][64][10];

  int w = threadIdx.x >> 6, lane = threadIdx.x & 63;
  int pair = w >> 1, half = w & 1;
  int tile = blockIdx.x * 2 + pair;
  int qt = tile & 127, bh = tile >> 7;
  int b = bh >> 2, h = bh & 3;
  int lr = lane & 15, kg = lane >> 4;
  int swz = (lr & 7) << 3;

  bf16x8 qraw = *(const bf16x8*)(q + (size_t)(b * T_ + qt * 16 + lr) * D_ + h * 32 + kg * 8);
  bf16x8 qf;
  #pragma unroll
  for (int e = 0; e < 8; e++) qf[e] = (__bf16)((float)qraw[e] * 0.17677669529663687f);

  const __bf16* kbase = k + (size_t)b * T_ * D_ + h * 32 + kg * 8;
  const __bf16* vbase = vT + (size_t)((b * H_ + h) * 32) * T_;

  float m = -1e30f, l = 0.f;
  f32x4 acc0 = {0, 0, 0, 0}, acc1 = {0, 0, 0, 0};
  const f32x4 zero = {0, 0, 0, 0};
  char* pb_base = (char*)&pbuf[w][0][0] + lr * 128;

  for (int it = 0; it < 16; it++) {
    int k0 = half * 1024 + it * 64;
    f32x4 s[4];
    #pragma unroll
    for (int kb = 0; kb < 4; kb++) {
      bf16x8 kf = *(const bf16x8*)(kbase + (size_t)(k0 + kb * 16 + lr) * D_);
      s[kb] = __builtin_amdgcn_mfma_f32_16x16x32_bf16(kf, qf, zero, 0, 0, 0);
    }
    float tm = s[0][0];
    #pragma unroll
    for (int kb = 0; kb < 4; kb++)
      #pragma unroll
      for (int r = 0; r < 4; r++) tm = fmaxf(tm, s[kb][r]);
    tm = fmaxf(tm, __shfl_xor(tm, 16, 64));
    tm = fmaxf(tm, __shfl_xor(tm, 32, 64));
    float mnew = fmaxf(m, tm);
    float corr = __expf(m - mnew);
    m = mnew;
    float rs = 0.f;
    #pragma unroll
    for (int kb = 0; kb < 4; kb++) {
      bf16x4 pk;
      #pragma unroll
      for (int r = 0; r < 4; r++) {
        float p = __expf(s[kb][r] - mnew);
        rs += p;
        pk[r] = (__bf16)p;
      }
      *(bf16x4*)(pb_base + (((kb * 16 + kg * 4) ^ swz) * 2)) = pk;
    }
    rs += __shfl_xor(rs, 16, 64);
    rs += __shfl_xor(rs, 32, 64);
    l = l * corr + rs;
    #pragma unroll
    for (int r = 0; r < 4; r++) { acc0[r] *= corr; acc1[r] *= corr; }

    const __bf16* vrow = vbase + k0 + kg * 8;
    #pragma unroll
    for (int c = 0; c < 2; c++) {
      bf16x8 pf = *(const bf16x8*)(pb_base + (((c * 32 + kg * 8) ^ swz) * 2));
      bf16x8 v0 = *(const bf16x8*)(vrow + (size_t)lr * T_ + c * 32);
      bf16x8 v1 = *(const bf16x8*)(vrow + (size_t)(16 + lr) * T_ + c * 32);
      acc0 = __builtin_amdgcn_mfma_f32_16x16x32_bf16(v0, pf, acc0, 0, 0, 0);
      acc1 = __builtin_amdgcn_mfma_f32_16x16x32_bf16(v1, pf, acc1, 0, 0, 0);
    }
  }

  if (half == 1) {
    float* mb = &mbuf[pair][lane][0];
    #pragma unroll
    for (int r = 0; r < 4; r++) { mb[r] = acc0[r]; mb[4 + r] = acc1[r]; }
    mb[8] = m; mb[9] = l;
  }
  __syncthreads();
  if (half == 0) {
    const float* mb = &mbuf[pair][lane][0];
    float m2 = mb[8], l2 = mb[9];
    float mm = fmaxf(m, m2);
    float c1 = __expf(m - mm), c2 = __expf(m2 - mm);
    float inv = 1.f / (l * c1 + l2 * c2);
    __bf16* crow = ctx + (size_t)(b * T_ + qt * 16 + lr) * D_ + h * 32 + kg * 4;
    #pragma unroll
    for (int r = 0; r < 4; r++) {
      crow[r]      = (__bf16)((acc0[r] * c1 + mb[r] * c2) * inv);
      crow[16 + r] = (__bf16)((acc1[r] * c1 + mb[4 + r] * c2) * inv);
    }
  }
}

// ---------------------------------------------------------------------------
extern "C" void kernel_launch(void* const* d_in, const int* in_sizes, int n_in,
                              void* d_out, int out_size, void* d_ws, size_t ws_size,
                              hipStream_t stream)
{
  const float* inputs = (const float*)d_in[0];
  const float* Wq = (const float*)d_in[1];
  const float* bq = (const float*)d_in[2];
  const float* Wk = (const float*)d_in[3];
  const float* bk = (const float*)d_in[4];
  const float* Wv = (const float*)d_in[5];
  const float* bv = (const float*)d_in[6];
  const float* Wo = (const float*)d_in[7];
  const float* bo = (const float*)d_in[8];
  const float* W1 = (const float*)d_in[9];
  const float* b1 = (const float*)d_in[10];
  const float* W2 = (const float*)d_in[11];
  const float* b2 = (const float*)d_in[12];
  const float* ln_g = (const float*)d_in[13];
  const float* ln_b = (const float*)d_in[14];
  float* out = (float*)d_out;

  char* ws = (char*)d_ws;
  size_t off = 0;
  auto alloc = [&](size_t bytes) {
    void* p = ws + off;
    off = (off + bytes + 255) & ~(size_t)255;
    return p;
  };
  const size_t ACT = (size_t)8192 * 128 * sizeof(__bf16);  // 2 MB
  __bf16* wt   = (__bf16*)alloc((size_t)6 * NB_ * 128 * 128 * sizeof(__bf16));
  __bf16* hln1 = (__bf16*)alloc(ACT);
  __bf16* qb   = (__bf16*)alloc(ACT);
  __bf16* kb   = (__bf16*)alloc(ACT);
  __bf16* vb   = (__bf16*)alloc(ACT);
  __bf16* ctxb = (__bf16*)alloc(ACT);
  __bf16* hln2 = (__bf16*)alloc(ACT);

  prep_weights<<<768, 256, 0, stream>>>(Wq, Wk, Wv, Wo, W1, W2, wt);
  pos_ln<<<2048, 256, 0, stream>>>(inputs, ln_g, ln_b, hln1);

  for (int i = 0; i < NB_; i++) {
    const __bf16* wto = wt + (size_t)(3 * NB_ + i) * 16384;
    const __bf16* wt1 = wt + (size_t)(4 * NB_ + i) * 16384;
    const __bf16* wt2 = wt + (size_t)(5 * NB_ + i) * 16384;

    gemm_qkv<<<dim3(512, 3), 64, 0, stream>>>(hln1, wt + (size_t)i * 16384,
                                              bq + i * 128, bk + i * 128, bv + i * 128,
                                              qb, kb, vb);
    attn2<<<1024, 256, 0, stream>>>(qb, kb, vb, ctxb);
    gemm_ln<<<512, 64, 0, stream>>>(ctxb, wto, bo + i * 128,
                                    ln_g + (size_t)(2 * i + 1) * 128,
                                    ln_b + (size_t)(2 * i + 1) * 128, hln2);
    if (i == 0) {
      ffn_fused<<<512, 64, 0, stream>>>(hln2, wt1, wt2, b1 + i * 128, b2 + i * 128,
                                        ln_g + 2 * 128, ln_b + 2 * 128, hln1, nullptr);
    } else {
      ffn_fused<<<512, 64, 0, stream>>>(hln2, wt1, wt2, b1 + i * 128, b2 + i * 128,
                                        ln_g + 3 * 128, ln_b + 3 * 128, nullptr, out);
    }
  }
}